// Round 4
// baseline (238.185 us; speedup 1.0000x reference)
//
#include <hip/hip_runtime.h>
#include <math.h>

// Problem constants (match reference setup_inputs)
#define NC      80
#define A_TOT   8400
#define B_TOT   32
#define BA      (B_TOT * A_TOT)    // 268800 anchors
#define NGRP    (BA / 16)          // 16800 wave-groups of 16 anchors
#define BLOCK   256
#define MAXNB   2100

__device__ __forceinline__ float wave_sum(float v) {
    #pragma unroll
    for (int off = 32; off > 0; off >>= 1) v += __shfl_down(v, off, 64);
    return v;
}

__global__ __launch_bounds__(BLOCK) void loss_main(
    const float* __restrict__ pred_dist,      // (B,A,64)
    const float* __restrict__ pred_scores,    // (B,A,80)
    const float* __restrict__ anchor_points,  // (A,2)
    const float* __restrict__ target_bboxes,  // (B,A,4)
    const float* __restrict__ target_scores,  // (B,A,80)
    float* __restrict__ partials,             // (4, nb) column-major
    int nb)
{
    __shared__ float red[4][4];

    const int tid  = threadIdx.x;
    const int lane = tid & 63;
    const int wid  = tid >> 6;
    const int q    = lane & 3;        // quarter-row within anchor
    const int alg  = lane >> 2;       // anchor within group (0..15)
    const int gw   = blockIdx.x * 4 + wid;   // global wave id
    const int nw   = nb * 4;

    const float4* ps4 = (const float4*)pred_scores;
    const float4* ts4 = (const float4*)target_scores;
    const float4* tb4 = (const float4*)target_bboxes;

    float cls_acc = 0.0f, iou_acc = 0.0f, dfl_acc = 0.0f, ts_acc = 0.0f;

    for (int grp = gw; grp < NGRP; grp += nw) {
        const long g0   = (long)grp * 16;
        const long base = (g0 + alg) * 20 + q;   // float4 units into (BA,80)

        // ---- focal BCE: 4 lanes/anchor, 5 float4 pairs each, no barriers ----
        float rs = 0.0f;
        #pragma unroll
        for (int j = 0; j < 5; ++j) {
            float4 pv  = ps4[base + 4 * j];
            float4 tv4 = ts4[base + 4 * j];
            float px[4] = {pv.x, pv.y, pv.z, pv.w};
            float tx[4] = {tv4.x, tv4.y, tv4.z, tv4.w};
            #pragma unroll
            for (int c = 0; c < 4; ++c) {
                float x  = px[c];
                float tv = tx[c];
                float e   = __expf(-fabsf(x));
                float ope = 1.0f + e;
                float lp  = __logf(ope);                  // log1p(e), e in (0,1]
                float sp  = fmaxf(x, 0.0f) + lp;          // softplus(x)
                float bce = sp - tv * x;                  // tv*sp(-x)+(1-tv)*sp(x)
                float pp  = __builtin_amdgcn_rcpf(ope);   // 1/(1+e) raw
                float p   = (x >= 0.0f) ? pp : (1.0f - pp);  // sigmoid(x)
                float u   = fmaf(p, 1.0f - 2.0f * tv, tv);   // 1 - p_t
                u = fmaxf(u, 0.0f);
                float af  = 0.75f - 0.5f * tv;               // alpha factor
                float su  = __builtin_amdgcn_sqrtf(u);
                cls_acc += bce * af * (u * su);              // * u^1.5
                rs += tv;
            }
        }
        rs += __shfl_xor(rs, 1);
        rs += __shfl_xor(rs, 2);            // all 4 lanes now hold rowsum
        if (q == 0) ts_acc += rs;

        // ---- fg anchors: whole wave processes each, one at a time ----
        unsigned long long m = __ballot(rs > 0.0f && q == 0);
        while (m) {
            int b = __ffsll((long long)m) - 1;
            m &= m - 1;
            float w = __shfl(rs, b);
            const long g = g0 + (b >> 2);
            const int  a = (int)(g % A_TOT);
            const float ax = anchor_points[2 * a];
            const float ay = anchor_points[2 * a + 1];
            const float4 tb = tb4[g];

            const int side = lane >> 4;     // 0..3 = l,t,r,b
            const int k    = lane & 15;     // bin

            float x = pred_dist[g * 64 + lane];   // one 256B coalesced row

            float tval = (side == 0) ? ax - tb.x :
                         (side == 1) ? ay - tb.y :
                         (side == 2) ? tb.z - ax : tb.w - ay;
            float tcl = fminf(fmaxf(tval, 0.0f), 14.99f);
            int   tl  = (int)tcl;
            float wl  = (float)(tl + 1) - tcl;
            float wr  = 1.0f - wl;

            // segmented (16-lane) softmax reductions
            float mx = x;
            mx = fmaxf(mx, __shfl_xor(mx, 1));
            mx = fmaxf(mx, __shfl_xor(mx, 2));
            mx = fmaxf(mx, __shfl_xor(mx, 4));
            mx = fmaxf(mx, __shfl_xor(mx, 8));

            float ex = __expf(x - mx);
            float se = ex;
            float nu = (float)k * ex;
            float ls = ((k == tl) ? wl : (k == tl + 1) ? wr : 0.0f) * x;
            #pragma unroll
            for (int off = 1; off < 16; off <<= 1) {
                se += __shfl_xor(se, off);
                nu += __shfl_xor(nu, off);
                ls += __shfl_xor(ls, off);
            }
            float dist = nu * __builtin_amdgcn_rcpf(se);
            float ce   = mx + __logf(se) - ls;

            float d0 = __shfl(dist, 0),  d1 = __shfl(dist, 16);
            float d2 = __shfl(dist, 32), d3 = __shfl(dist, 48);
            float c0 = __shfl(ce, 0),    c1 = __shfl(ce, 16);
            float c2 = __shfl(ce, 32),   c3 = __shfl(ce, 48);

            if (lane == 0) {
                dfl_acc += 0.25f * (c0 + c1 + c2 + c3) * w;

                const float eps = 1e-7f;
                float px1 = ax - d0, py1 = ay - d1;
                float px2 = ax + d2, py2 = ay + d3;
                float w1 = px2 - px1, h1 = py2 - py1 + eps;
                float w2 = tb.z - tb.x, h2 = tb.w - tb.y + eps;
                float iw = fmaxf(fminf(px2, tb.z) - fmaxf(px1, tb.x), 0.0f);
                float ih = fmaxf(fminf(py2, tb.w) - fmaxf(py1, tb.y), 0.0f);
                float inter = iw * ih;
                float uni = w1 * h1 + w2 * h2 - inter + eps;
                float iou = inter / uni;
                float cw = fmaxf(px2, tb.z) - fminf(px1, tb.x);
                float ch = fmaxf(py2, tb.w) - fminf(py1, tb.y);
                float c2d = cw * cw + ch * ch + eps;
                float dx = tb.x + tb.z - px1 - px2;
                float dy = tb.y + tb.w - py1 - py2;
                float rho2 = (dx * dx + dy * dy) * 0.25f;
                const float c4pi2 = 0.40528473456935109f;  // 4/pi^2
                float dat = atanf(w2 / h2) - atanf(w1 / h1);
                float v = c4pi2 * dat * dat;
                float alpha = v / (v - iou + (1.0f + eps));
                float ciou = iou - (rho2 / c2d + v * alpha);
                iou_acc += (1.0f - ciou) * w;
            }
        }
    }

    // ---- block reduce 4 scalars, write own partial slot (no atomics) ----
    float v0 = wave_sum(iou_acc);
    float v1 = wave_sum(cls_acc);
    float v2 = wave_sum(ts_acc);
    float v3 = wave_sum(dfl_acc);
    if (lane == 0) { red[0][wid] = v0; red[1][wid] = v1; red[2][wid] = v2; red[3][wid] = v3; }
    __syncthreads();
    if (tid == 0) {
        float r0 = 0, r1 = 0, r2 = 0, r3 = 0;
        #pragma unroll
        for (int i = 0; i < 4; ++i) { r0 += red[0][i]; r1 += red[1][i]; r2 += red[2][i]; r3 += red[3][i]; }
        partials[0 * nb + blockIdx.x] = r0;
        partials[1 * nb + blockIdx.x] = r1;
        partials[2 * nb + blockIdx.x] = r2;
        partials[3 * nb + blockIdx.x] = r3;
    }
}

__global__ __launch_bounds__(BLOCK) void loss_reduce(
    const float* __restrict__ partials, int nb, float* __restrict__ out)
{
    __shared__ float red[4][4];
    int tid = threadIdx.x;
    float s0 = 0, s1 = 0, s2 = 0, s3 = 0;
    for (int i = tid; i < nb; i += BLOCK) {
        s0 += partials[i];
        s1 += partials[nb + i];
        s2 += partials[2 * nb + i];
        s3 += partials[3 * nb + i];
    }
    s0 = wave_sum(s0); s1 = wave_sum(s1); s2 = wave_sum(s2); s3 = wave_sum(s3);
    int wid = tid >> 6;
    if ((tid & 63) == 0) { red[0][wid] = s0; red[1][wid] = s1; red[2][wid] = s2; red[3][wid] = s3; }
    __syncthreads();
    if (tid == 0) {
        float r0 = 0, r1 = 0, r2 = 0, r3 = 0;
        #pragma unroll
        for (int i = 0; i < 4; ++i) { r0 += red[0][i]; r1 += red[1][i]; r2 += red[2][i]; r3 += red[3][i]; }
        float tss = fmaxf(r2, 1.0f);
        out[0] = 7.5f * r0 / tss;   // box
        out[1] = 0.5f * r1 / tss;   // cls
        out[2] = 1.5f * r3 / tss;   // dfl
    }
}

extern "C" void kernel_launch(void* const* d_in, const int* in_sizes, int n_in,
                              void* d_out, int out_size, void* d_ws, size_t ws_size,
                              hipStream_t stream) {
    const float* pred_dist     = (const float*)d_in[0];
    const float* pred_scores   = (const float*)d_in[1];
    const float* anchor_points = (const float*)d_in[2];
    const float* target_bboxes = (const float*)d_in[3];
    const float* target_scores = (const float*)d_in[4];
    // d_in[5] (fg_mask) unused: target_scores is exactly zero off-mask.

    int nb = (int)(ws_size / (4 * sizeof(float)));
    if (nb > MAXNB) nb = MAXNB;
    if (nb < 1) nb = 1;

    float* partials = (float*)d_ws;   // fully overwritten each launch
    loss_main<<<nb, BLOCK, 0, stream>>>(
        pred_dist, pred_scores, anchor_points, target_bboxes, target_scores,
        partials, nb);
    loss_reduce<<<1, BLOCK, 0, stream>>>(partials, nb, (float*)d_out);
}

// Round 6
// 219.467 us; speedup vs baseline: 1.0853x; 1.0853x over previous
//
#include <hip/hip_runtime.h>
#include <math.h>

// Problem constants (match reference setup_inputs)
#define NC      80
#define A_TOT   8400
#define B_TOT   32
#define BA      (B_TOT * A_TOT)    // 268800 anchors
#define NGRP    (BA / 16)          // 16800 wave-groups of 16 anchors
#define BLOCK   256
#define MAXNB   4200               // 16800 waves -> 1 group per wave

__device__ __forceinline__ float wave_sum(float v) {
    #pragma unroll
    for (int off = 32; off > 0; off >>= 1) v += __shfl_down(v, off, 64);
    return v;
}

__global__ __launch_bounds__(BLOCK) void loss_main(
    const float* __restrict__ pred_dist,      // (B,A,64)
    const float* __restrict__ pred_scores,    // (B,A,80)
    const float* __restrict__ anchor_points,  // (A,2)
    const float* __restrict__ target_bboxes,  // (B,A,4)
    const float* __restrict__ target_scores,  // (B,A,80)
    const int* __restrict__ fgmask,           // (B,A) bool stored as int32
    float* __restrict__ partials,             // (4, nb) column-major
    int nb)
{
    __shared__ float red[4][4];

    const int tid  = threadIdx.x;
    const int lane = tid & 63;
    const int wid  = tid >> 6;
    const int q    = lane & 3;        // quarter-row within anchor
    const int alg  = lane >> 2;       // anchor within group (0..15)
    const int gw   = blockIdx.x * 4 + wid;   // global wave id
    const int nw   = nb * 4;

    const float4* ps4 = (const float4*)pred_scores;
    const float4* ts4 = (const float4*)target_scores;
    const float4* tb4 = (const float4*)target_bboxes;

    float cls_acc = 0.0f, iou_acc = 0.0f, dfl_acc = 0.0f, ts_acc = 0.0f;

    for (int grp = gw; grp < NGRP; grp += nw) {
        const long g0   = (long)grp * 16;
        const long base = (g0 + alg) * 20 + q;   // float4 units into (BA,80)

        // fg gate for this quartet's anchor (ts==0 exactly where fg==0)
        const int fgm = fgmask[g0 + alg];

        float4 tvl[5];
        #pragma unroll
        for (int j = 0; j < 5; ++j) tvl[j] = make_float4(0.f, 0.f, 0.f, 0.f);
        if (fgm) {
            #pragma unroll
            for (int j = 0; j < 5; ++j) tvl[j] = ts4[base + 4 * j];
        }

        // ---- focal BCE: 4 lanes/anchor, 5 float4 each, no barriers ----
        float rs = 0.0f;
        #pragma unroll
        for (int j = 0; j < 5; ++j) {
            float4 pv = ps4[base + 4 * j];
            float px[4] = {pv.x, pv.y, pv.z, pv.w};
            float tx[4] = {tvl[j].x, tvl[j].y, tvl[j].z, tvl[j].w};
            #pragma unroll
            for (int c = 0; c < 4; ++c) {
                float x  = px[c];
                float tv = tx[c];
                float e   = __expf(-fabsf(x));
                float ope = 1.0f + e;
                float lp  = __logf(ope);                  // log1p(e), e in (0,1]
                float sp  = fmaxf(x, 0.0f) + lp;          // softplus(x)
                float bce = sp - tv * x;                  // tv*sp(-x)+(1-tv)*sp(x)
                float pp  = __builtin_amdgcn_rcpf(ope);   // 1/(1+e) raw
                float p   = (x >= 0.0f) ? pp : (1.0f - pp);  // sigmoid(x)
                float u   = fmaf(p, 1.0f - 2.0f * tv, tv);   // 1 - p_t
                u = fmaxf(u, 0.0f);
                float af  = 0.75f - 0.5f * tv;               // alpha factor
                float su  = __builtin_amdgcn_sqrtf(u);
                cls_acc += bce * af * (u * su);              // * u^1.5
                rs += tv;
            }
        }
        rs += __shfl_xor(rs, 1);
        rs += __shfl_xor(rs, 2);            // all 4 lanes hold anchor rowsum
        if (q == 0) ts_acc += rs;

        // ---- fg anchors: whole wave processes each, one at a time ----
        unsigned long long m = __ballot(rs > 0.0f && q == 0);
        while (m) {
            int b = __ffsll((long long)m) - 1;
            m &= m - 1;
            float w = __shfl(rs, b);
            const long g = g0 + (b >> 2);
            const int  a = (int)(g % A_TOT);
            const float ax = anchor_points[2 * a];
            const float ay = anchor_points[2 * a + 1];
            const float4 tb = tb4[g];

            const int side = lane >> 4;     // 0..3 = l,t,r,b
            const int k    = lane & 15;     // bin

            float x = pred_dist[g * 64 + lane];   // one 256B coalesced row

            float tval = (side == 0) ? ax - tb.x :
                         (side == 1) ? ay - tb.y :
                         (side == 2) ? tb.z - ax : tb.w - ay;
            float tcl = fminf(fmaxf(tval, 0.0f), 14.99f);
            int   tl  = (int)tcl;
            float wl  = (float)(tl + 1) - tcl;
            float wr  = 1.0f - wl;

            // segmented (16-lane) softmax reductions
            float mx = x;
            mx = fmaxf(mx, __shfl_xor(mx, 1));
            mx = fmaxf(mx, __shfl_xor(mx, 2));
            mx = fmaxf(mx, __shfl_xor(mx, 4));
            mx = fmaxf(mx, __shfl_xor(mx, 8));

            float ex = __expf(x - mx);
            float se = ex;
            float nu = (float)k * ex;
            float ls = ((k == tl) ? wl : (k == tl + 1) ? wr : 0.0f) * x;
            #pragma unroll
            for (int off = 1; off < 16; off <<= 1) {
                se += __shfl_xor(se, off);
                nu += __shfl_xor(nu, off);
                ls += __shfl_xor(ls, off);
            }
            float dist = nu * __builtin_amdgcn_rcpf(se);
            float ce   = mx + __logf(se) - ls;

            float d0 = __shfl(dist, 0),  d1 = __shfl(dist, 16);
            float d2 = __shfl(dist, 32), d3 = __shfl(dist, 48);
            float c0 = __shfl(ce, 0),    c1 = __shfl(ce, 16);
            float c2 = __shfl(ce, 32),   c3 = __shfl(ce, 48);

            if (lane == 0) {
                dfl_acc += 0.25f * (c0 + c1 + c2 + c3) * w;

                const float eps = 1e-7f;
                float px1 = ax - d0, py1 = ay - d1;
                float px2 = ax + d2, py2 = ay + d3;
                float w1 = px2 - px1, h1 = py2 - py1 + eps;
                float w2 = tb.z - tb.x, h2 = tb.w - tb.y + eps;
                float iw = fmaxf(fminf(px2, tb.z) - fmaxf(px1, tb.x), 0.0f);
                float ih = fmaxf(fminf(py2, tb.w) - fmaxf(py1, tb.y), 0.0f);
                float inter = iw * ih;
                float uni = w1 * h1 + w2 * h2 - inter + eps;
                float iou = inter / uni;
                float cw = fmaxf(px2, tb.z) - fminf(px1, tb.x);
                float ch = fmaxf(py2, tb.w) - fminf(py1, tb.y);
                float c2d = cw * cw + ch * ch + eps;
                float dx = tb.x + tb.z - px1 - px2;
                float dy = tb.y + tb.w - py1 - py2;
                float rho2 = (dx * dx + dy * dy) * 0.25f;
                const float c4pi2 = 0.40528473456935109f;  // 4/pi^2
                float dat = atanf(w2 / h2) - atanf(w1 / h1);
                float v = c4pi2 * dat * dat;
                float alpha = v / (v - iou + (1.0f + eps));
                float ciou = iou - (rho2 / c2d + v * alpha);
                iou_acc += (1.0f - ciou) * w;
            }
        }
    }

    // ---- block reduce 4 scalars, write own partial slot (no atomics) ----
    float v0 = wave_sum(iou_acc);
    float v1 = wave_sum(cls_acc);
    float v2 = wave_sum(ts_acc);
    float v3 = wave_sum(dfl_acc);
    if (lane == 0) { red[0][wid] = v0; red[1][wid] = v1; red[2][wid] = v2; red[3][wid] = v3; }
    __syncthreads();
    if (tid == 0) {
        float r0 = 0, r1 = 0, r2 = 0, r3 = 0;
        #pragma unroll
        for (int i = 0; i < 4; ++i) { r0 += red[0][i]; r1 += red[1][i]; r2 += red[2][i]; r3 += red[3][i]; }
        partials[0 * nb + blockIdx.x] = r0;
        partials[1 * nb + blockIdx.x] = r1;
        partials[2 * nb + blockIdx.x] = r2;
        partials[3 * nb + blockIdx.x] = r3;
    }
}

__global__ __launch_bounds__(BLOCK) void loss_reduce(
    const float* __restrict__ partials, int nb, float* __restrict__ out)
{
    __shared__ float red[4][4];
    int tid = threadIdx.x;
    float s0 = 0, s1 = 0, s2 = 0, s3 = 0;
    for (int i = tid; i < nb; i += BLOCK) {
        s0 += partials[i];
        s1 += partials[nb + i];
        s2 += partials[2 * nb + i];
        s3 += partials[3 * nb + i];
    }
    s0 = wave_sum(s0); s1 = wave_sum(s1); s2 = wave_sum(s2); s3 = wave_sum(s3);
    int wid = tid >> 6;
    if ((tid & 63) == 0) { red[0][wid] = s0; red[1][wid] = s1; red[2][wid] = s2; red[3][wid] = s3; }
    __syncthreads();
    if (tid == 0) {
        float r0 = 0, r1 = 0, r2 = 0, r3 = 0;
        #pragma unroll
        for (int i = 0; i < 4; ++i) { r0 += red[0][i]; r1 += red[1][i]; r2 += red[2][i]; r3 += red[3][i]; }
        float tss = fmaxf(r2, 1.0f);
        out[0] = 7.5f * r0 / tss;   // box
        out[1] = 0.5f * r1 / tss;   // cls
        out[2] = 1.5f * r3 / tss;   // dfl
    }
}

extern "C" void kernel_launch(void* const* d_in, const int* in_sizes, int n_in,
                              void* d_out, int out_size, void* d_ws, size_t ws_size,
                              hipStream_t stream) {
    const float* pred_dist     = (const float*)d_in[0];
    const float* pred_scores   = (const float*)d_in[1];
    const float* anchor_points = (const float*)d_in[2];
    const float* target_bboxes = (const float*)d_in[3];
    const float* target_scores = (const float*)d_in[4];
    const int*   fgmask        = (const int*)d_in[5];   // bool -> int32 per harness

    int nb = (int)(ws_size / (4 * sizeof(float)));
    if (nb > MAXNB) nb = MAXNB;
    if (nb < 1) nb = 1;

    float* partials = (float*)d_ws;   // fully overwritten each launch
    loss_main<<<nb, BLOCK, 0, stream>>>(
        pred_dist, pred_scores, anchor_points, target_bboxes, target_scores,
        fgmask, partials, nb);
    loss_reduce<<<1, BLOCK, 0, stream>>>(partials, nb, (float*)d_out);
}